// Round 3
// baseline (134.971 us; speedup 1.0000x reference)
//
#include <hip/hip_runtime.h>
#include <hip/hip_bf16.h>

// NT-Xent loss: z1,z2 [4096,256] fp32 -> scalar loss.
// R6: R5's empty-asm pin failed (VGPR still 112: LLVM sank each {load,pin}
// pair into the k-loop as a unit -> still 8 serialized L2 latencies/block).
// Fix: the B loads are now OPAQUE inline-asm volatile global_load_dwordx4.
// Volatile asm ops are strictly ordered w.r.t. each other, so:
//   32x asm loads -> asm s_waitcnt vmcnt(0) -> sched_barrier(0) -> barrier
// cannot be sunk or reordered; the 128 B-panel VGPRs are live from the wait
// to their MFMA uses. Inline-asm loads bypass compiler vmcnt tracking, so the
// manual s_waitcnt is REQUIRED (it also drains the A global_load_lds issued
// first; vmcnt completes in issue order). setprio(1) wraps each kstep's MFMA
// cluster (barrier-free phase-skewed waves = the regime where T5 pays).
// Kept: triangle symmetry, fused exp/row/col sums, XOR-swizzled A tile,
// bijective XCD chunk swizzle, pair-dot folded into k_normalize.

#define TWO_N 8192
#define NPAIR 4096
#define DDIM  256
#define NT    64                    // 128-row tiles per dim
#define NBLK  (NT * (NT + 1) / 2)   // 2080 upper-triangle tiles
#define INV_T 2.0f

typedef __attribute__((ext_vector_type(8))) short bf16x8;
typedef __attribute__((ext_vector_type(4))) float f32x4;

typedef __attribute__((address_space(1))) void gvoid_t;
typedef __attribute__((address_space(3))) void lvoid_t;

__device__ __forceinline__ void gload_lds16(const void* g, void* l) {
    __builtin_amdgcn_global_load_lds((gvoid_t*)g, (lvoid_t*)l, 16, 0, 0);
}

// ---------------- Kernel 1: normalize + quantize + pair-dot + zero scratch --
// grid 1024 x 256: one wave per PAIR i (handles rows i and i+4096).
__global__ void k_normalize(const float* __restrict__ z1,
                            const float* __restrict__ z2,
                            __hip_bfloat16* __restrict__ zn,
                            float* __restrict__ e_diag,
                            float* __restrict__ pos,
                            float* __restrict__ row_sumexp,
                            float* __restrict__ out) {
    if (threadIdx.x < 8) row_sumexp[blockIdx.x * 8 + threadIdx.x] = 0.0f;
    if (blockIdx.x == 0 && threadIdx.x == 0) out[0] = 0.0f;

    const int w    = threadIdx.x >> 6;
    const int lane = threadIdx.x & 63;
    const int i    = blockIdx.x * 4 + w;

    float4 a = ((const float4*)(z1 + (size_t)i * DDIM))[lane];
    float4 b = ((const float4*)(z2 + (size_t)i * DDIM))[lane];

    float s1 = a.x * a.x + a.y * a.y + a.z * a.z + a.w * a.w;
    float s2 = b.x * b.x + b.y * b.y + b.z * b.z + b.w * b.w;
    float dd = a.x * b.x + a.y * b.y + a.z * b.z + a.w * b.w;
#pragma unroll
    for (int m = 1; m < 64; m <<= 1) {
        s1 += __shfl_xor(s1, m, 64);
        s2 += __shfl_xor(s2, m, 64);
        dd += __shfl_xor(dd, m, 64);
    }

    float inv1 = 1.0f / fmaxf(sqrtf(s1), 1e-8f);   // matches reference eps
    float inv2 = 1.0f / fmaxf(sqrtf(s2), 1e-8f);

    __hip_bfloat16 q1[4], q2[4];
    q1[0] = __float2bfloat16(a.x * inv1); q1[1] = __float2bfloat16(a.y * inv1);
    q1[2] = __float2bfloat16(a.z * inv1); q1[3] = __float2bfloat16(a.w * inv1);
    q2[0] = __float2bfloat16(b.x * inv2); q2[1] = __float2bfloat16(b.y * inv2);
    q2[2] = __float2bfloat16(b.z * inv2); q2[3] = __float2bfloat16(b.w * inv2);

    float qs1 = 0.0f, qs2 = 0.0f;
#pragma unroll
    for (int j = 0; j < 4; ++j) {
        float f1 = __bfloat162float(q1[j]);
        float f2 = __bfloat162float(q2[j]);
        qs1 += f1 * f1;
        qs2 += f2 * f2;
    }
#pragma unroll
    for (int m = 1; m < 64; m <<= 1) {
        qs1 += __shfl_xor(qs1, m, 64);
        qs2 += __shfl_xor(qs2, m, 64);
    }

    *reinterpret_cast<uint2*>(zn + (size_t)i * DDIM + lane * 4) =
        *reinterpret_cast<uint2*>(q1);
    *reinterpret_cast<uint2*>(zn + (size_t)(i + NPAIR) * DDIM + lane * 4) =
        *reinterpret_cast<uint2*>(q2);

    if (lane == 0) {
        e_diag[i]         = __expf(qs1 * INV_T);   // matches GEMM's bf16 self-dot
        e_diag[i + NPAIR] = __expf(qs2 * INV_T);
        pos[i]            = dd * inv1 * inv2 * INV_T;  // positive-pair term, pure fp32
    }
}

// ---------------- Kernel 2: symmetric MFMA self-GEMM + exp + row/col sums ----
// 2080 blocks (upper-triangle 128x128 tiles), 256 threads (2x2 waves of 64x64).
// A-tile full K in LDS (swizzled), staged with global_load_lds(16B).
// B panel fully prefetched into registers via OPAQUE asm loads (R6).
__global__ __launch_bounds__(256, 2)
void k_gemm_sumexp(const __hip_bfloat16* __restrict__ zn,
                   float* __restrict__ row_sumexp) {
    __shared__ __align__(128) __hip_bfloat16 Asmem[128 * DDIM];   // 64 KB

    const int tid  = threadIdx.x;
    const int lane = tid & 63;
    const int w    = tid >> 6;
    const int wr   = w >> 1;          // wave row-half (0/1)
    const int wc   = w & 1;           // wave col-half (0/1)
    const int lr   = lane & 15;
    const int quad = lane >> 4;

    // --- XCD chunk swizzle: 2080 = 8*260 exactly, bijective. ---
    int b = (blockIdx.x & 7) * (NBLK / 8) + (blockIdx.x >> 3);

    // --- triangular decode: block b -> (rt, ct), rt <= ct (verified R2) ---
    int rt = (int)(64.5f - sqrtf(64.5f * 64.5f - 2.0f * (float)b));
    if (rt < 0) rt = 0;
    if (rt > NT - 1) rt = NT - 1;
    while (rt > 0 && NT * rt - (rt * (rt - 1)) / 2 > b) --rt;
    while (NT * (rt + 1) - ((rt + 1) * rt) / 2 <= b) ++rt;
    const int ct   = rt + (b - (NT * rt - (rt * (rt - 1)) / 2));
    const bool diag = (rt == ct);

    const int row_base = rt * 128;
    const int col_base = ct * 128;

    // --- stage A tile FIRST: slot s = j*256+tid -> row = j*8 + (tid>>5),
    //     c' = tid&31; source chunk ck per-thread constant. 16 x 16B/lane.
    //     Issued before B so the single vmcnt(0) below drains both. ---
    {
        const int ck = (tid & 24) | ((tid & 7) ^ (tid >> 5));
        const char* gA = (const char*)(zn + (size_t)row_base * DDIM)
                       + (tid >> 5) * (DDIM * 2) + ck * 16;
        char* lA = (char*)Asmem + tid * 16;
#pragma unroll
        for (int j = 0; j < 16; ++j)
            gload_lds16(gA + (size_t)j * 8 * (DDIM * 2), lA + j * 4096);
    }

    // --- B fragment base pointers: row = col_base + wc*64 + ni*16 + lr ---
    const __hip_bfloat16* gB[4];
#pragma unroll
    for (int ni = 0; ni < 4; ++ni)
        gB[ni] = zn + (size_t)(col_base + wc * 64 + ni * 16 + lr) * DDIM + quad * 8;

    // --- issue the FULL B panel as OPAQUE loads: 32 x 16B per lane.
    //     asm volatile ops are mutually ordered; these cannot be sunk into
    //     the k-loop. Outputs (128 VGPRs) stay live until their MFMA uses. ---
    bf16x8 Bfr[8][4];
#pragma unroll
    for (int ks = 0; ks < 8; ++ks)
#pragma unroll
        for (int ni = 0; ni < 4; ++ni) {
            const __hip_bfloat16* p = gB[ni] + ks * 32;   // +64B per kstep
            asm volatile("global_load_dwordx4 %0, %1, off"
                         : "=v"(Bfr[ks][ni]) : "v"(p));
        }

    // --- drain EVERYTHING in one latency event (A staging + B panel).
    //     Inline-asm loads are invisible to compiler vmcnt tracking, so this
    //     manual wait is REQUIRED; sched_barrier(0) stops MFMA hoisting. ---
    asm volatile("s_waitcnt vmcnt(0)" ::: "memory");
    __builtin_amdgcn_sched_barrier(0);

    __syncthreads();   // the ONLY barrier (A already drained above)

    // --- A fragment LDS byte offsets (swizzled) ---
    // A(mi,kstep): row = wr*64+mi*16+lr, byte = row*512 + (kstep>>1)*128
    //              + [ (quad ^ (lr&7)) ^ ((kstep&1)<<2) ] * 16
    int pa[4];
#pragma unroll
    for (int mi = 0; mi < 4; ++mi)
        pa[mi] = (wr * 64 + mi * 16 + lr) * (DDIM * 2) + ((quad ^ (lr & 7)) << 4);

    f32x4 acc[4][4];
#pragma unroll
    for (int mi = 0; mi < 4; ++mi)
#pragma unroll
        for (int ni = 0; ni < 4; ++ni) acc[mi][ni] = (f32x4){0.f, 0.f, 0.f, 0.f};

    bf16x8 afc[4];
#pragma unroll
    for (int mi = 0; mi < 4; ++mi)
        afc[mi] = *(const bf16x8*)((const char*)Asmem + pa[mi]);

#pragma unroll
    for (int kstep = 0; kstep < 8; ++kstep) {
        bf16x8 afn[4];
        if (kstep < 7) {
            const int kn   = kstep + 1;
            const int koff = ((kn >> 1) << 7);
            const int kx   = ((kn & 1) << 6);
#pragma unroll
            for (int mi = 0; mi < 4; ++mi)
                afn[mi] = *(const bf16x8*)((const char*)Asmem + ((pa[mi] ^ kx) + koff));
        }
        __builtin_amdgcn_s_setprio(1);
#pragma unroll
        for (int mi = 0; mi < 4; ++mi)
#pragma unroll
            for (int ni = 0; ni < 4; ++ni)
                acc[mi][ni] = __builtin_amdgcn_mfma_f32_16x16x32_bf16(
                    afc[mi], Bfr[kstep][ni], acc[mi][ni], 0, 0, 0);
        __builtin_amdgcn_s_setprio(0);
        if (kstep < 7) {
#pragma unroll
            for (int mi = 0; mi < 4; ++mi) afc[mi] = afn[mi];
        }
    }

    // --- epilogue: e = exp(2*dot); row-sums always, col-sums if off-diag ---
    // C/D layout (verified R1/R2): col = lane&15, row = quad*4 + reg.
    float rs[4][4];
    float cs[4];
#pragma unroll
    for (int mi = 0; mi < 4; ++mi)
#pragma unroll
        for (int r = 0; r < 4; ++r) rs[mi][r] = 0.0f;
#pragma unroll
    for (int ni = 0; ni < 4; ++ni) cs[ni] = 0.0f;

#pragma unroll
    for (int mi = 0; mi < 4; ++mi)
#pragma unroll
        for (int ni = 0; ni < 4; ++ni)
#pragma unroll
            for (int r = 0; r < 4; ++r) {
                float e = __expf(acc[mi][ni][r] * INV_T);
                rs[mi][r] += e;
                cs[ni] += e;
            }

    // row sums: reduce over lane bits 0..3 (the 16 columns)
#pragma unroll
    for (int mi = 0; mi < 4; ++mi) {
#pragma unroll
        for (int r = 0; r < 4; ++r) {
            float v = rs[mi][r];
            v += __shfl_xor(v, 1, 64);
            v += __shfl_xor(v, 2, 64);
            v += __shfl_xor(v, 4, 64);
            v += __shfl_xor(v, 8, 64);
            if (lr == 0) {
                int row = row_base + wr * 64 + mi * 16 + quad * 4 + r;
                atomicAdd(&row_sumexp[row], v);
            }
        }
    }

    // col sums: reduce over lane bits 4..5
    if (!diag) {
#pragma unroll
        for (int ni = 0; ni < 4; ++ni) {
            float v = cs[ni];
            v += __shfl_xor(v, 16, 64);
            v += __shfl_xor(v, 32, 64);
            if (quad == 0) {
                int col = col_base + wc * 64 + ni * 16 + lr;
                atomicAdd(&row_sumexp[col], v);
            }
        }
    }
}

// ---------------- Kernel 3: tiny finisher ----------------
// grid 16 x 256: one thread per pair index.
__global__ void k_final(const float* __restrict__ row_sumexp,
                        const float* __restrict__ e_diag,
                        const float* __restrict__ pos,
                        float* __restrict__ out) {
    const int i    = blockIdx.x * 256 + threadIdx.x;   // 0..4095
    const int w    = threadIdx.x >> 6;
    const int lane = threadIdx.x & 63;

    float t = logf(row_sumexp[i] - e_diag[i])
            + logf(row_sumexp[i + NPAIR] - e_diag[i + NPAIR])
            - 2.0f * pos[i];
#pragma unroll
    for (int m = 1; m < 64; m <<= 1) t += __shfl_xor(t, m, 64);

    __shared__ float ps[4];
    if (lane == 0) ps[w] = t;
    __syncthreads();
    if (threadIdx.x == 0) {
        float s = (ps[0] + ps[1] + ps[2] + ps[3]) * (1.0f / (float)TWO_N);
        atomicAdd(out, s);
    }
}

extern "C" void kernel_launch(void* const* d_in, const int* in_sizes, int n_in,
                              void* d_out, int out_size, void* d_ws, size_t ws_size,
                              hipStream_t stream) {
    const float* z1 = (const float*)d_in[0];
    const float* z2 = (const float*)d_in[1];
    float* out = (float*)d_out;

    char* ws = (char*)d_ws;
    __hip_bfloat16* zn  = (__hip_bfloat16*)ws;                       // 4 MB
    float* row_sumexp   = (float*)(ws + (size_t)TWO_N * DDIM * 2);   // 32 KB
    float* e_diag       = row_sumexp + TWO_N;                        // 32 KB
    float* pos          = e_diag + TWO_N;                            // 16 KB

    k_normalize<<<NPAIR / 4, 256, 0, stream>>>(z1, z2, zn, e_diag, pos,
                                               row_sumexp, out);
    k_gemm_sumexp<<<NBLK, 256, 0, stream>>>(zn, row_sumexp);
    k_final<<<NPAIR / 256, 256, 0, stream>>>(row_sumexp, e_diag, pos, out);
}

// Round 4
// 128.638 us; speedup vs baseline: 1.0492x; 1.0492x over previous
//
#include <hip/hip_runtime.h>
#include <hip/hip_bf16.h>

// NT-Xent loss: z1,z2 [4096,256] fp32 -> scalar loss.
// R7: persistent-block GEMM. R4-R6 showed 128-reg B panels can't coexist with
// 2 blocks/CU (256-reg wall); R6's AGPR shuffle + occupancy loss regressed.
// Restructure instead:
//  - grid 256 x 512 threads (8 waves, 2x4 over the 128x128 tile): per-wave B
//    panel is 16 frags = 64 VGPRs -> full-panel residency finally fits.
//  - persistent: each block owns ~8 consecutive triangle tiles; A-panel staged
//    once per rt-run (barrier only on restage); NO per-tile barriers, waves
//    drift freely.
//  - cross-tile pipeline: issue tile-i B loads (opaque asm, ordered) -> run
//    tile-(i-1) epilogue (exp+shuffles+atomics, ~3k cy, hides B latency) ->
//    counted s_waitcnt vmcnt(16) (atomics issued after B; in-order vmcnt
//    semantics guarantee all B done) -> sched_barrier(0) -> pure LDS+MFMA
//    k-loop. vmcnt(0) only on the rare restage path.
// Kept: triangle symmetry, XOR-swizzled A tile, fused exp/row/col sums,
// pair-dot in k_normalize.

#define TWO_N 8192
#define NPAIR 4096
#define DDIM  256
#define NT    64                    // 128-row tiles per dim
#define NBLK  (NT * (NT + 1) / 2)   // 2080 upper-triangle tiles
#define INV_T 2.0f
#define GEMM_GRID 256               // persistent blocks, 1 per CU

typedef __attribute__((ext_vector_type(8))) short bf16x8;
typedef __attribute__((ext_vector_type(4))) float f32x4;

typedef __attribute__((address_space(1))) void gvoid_t;
typedef __attribute__((address_space(3))) void lvoid_t;

__device__ __forceinline__ void gload_lds16(const void* g, void* l) {
    __builtin_amdgcn_global_load_lds((gvoid_t*)g, (lvoid_t*)l, 16, 0, 0);
}

// ---------------- Kernel 1: normalize + quantize + pair-dot + zero scratch --
// grid 1024 x 256: one wave per PAIR i (handles rows i and i+4096).
__global__ void k_normalize(const float* __restrict__ z1,
                            const float* __restrict__ z2,
                            __hip_bfloat16* __restrict__ zn,
                            float* __restrict__ e_diag,
                            float* __restrict__ pos,
                            float* __restrict__ row_sumexp,
                            float* __restrict__ out) {
    if (threadIdx.x < 8) row_sumexp[blockIdx.x * 8 + threadIdx.x] = 0.0f;
    if (blockIdx.x == 0 && threadIdx.x == 0) out[0] = 0.0f;

    const int w    = threadIdx.x >> 6;
    const int lane = threadIdx.x & 63;
    const int i    = blockIdx.x * 4 + w;

    float4 a = ((const float4*)(z1 + (size_t)i * DDIM))[lane];
    float4 b = ((const float4*)(z2 + (size_t)i * DDIM))[lane];

    float s1 = a.x * a.x + a.y * a.y + a.z * a.z + a.w * a.w;
    float s2 = b.x * b.x + b.y * b.y + b.z * b.z + b.w * b.w;
    float dd = a.x * b.x + a.y * b.y + a.z * b.z + a.w * b.w;
#pragma unroll
    for (int m = 1; m < 64; m <<= 1) {
        s1 += __shfl_xor(s1, m, 64);
        s2 += __shfl_xor(s2, m, 64);
        dd += __shfl_xor(dd, m, 64);
    }

    float inv1 = 1.0f / fmaxf(sqrtf(s1), 1e-8f);   // matches reference eps
    float inv2 = 1.0f / fmaxf(sqrtf(s2), 1e-8f);

    __hip_bfloat16 q1[4], q2[4];
    q1[0] = __float2bfloat16(a.x * inv1); q1[1] = __float2bfloat16(a.y * inv1);
    q1[2] = __float2bfloat16(a.z * inv1); q1[3] = __float2bfloat16(a.w * inv1);
    q2[0] = __float2bfloat16(b.x * inv2); q2[1] = __float2bfloat16(b.y * inv2);
    q2[2] = __float2bfloat16(b.z * inv2); q2[3] = __float2bfloat16(b.w * inv2);

    float qs1 = 0.0f, qs2 = 0.0f;
#pragma unroll
    for (int j = 0; j < 4; ++j) {
        float f1 = __bfloat162float(q1[j]);
        float f2 = __bfloat162float(q2[j]);
        qs1 += f1 * f1;
        qs2 += f2 * f2;
    }
#pragma unroll
    for (int m = 1; m < 64; m <<= 1) {
        qs1 += __shfl_xor(qs1, m, 64);
        qs2 += __shfl_xor(qs2, m, 64);
    }

    *reinterpret_cast<uint2*>(zn + (size_t)i * DDIM + lane * 4) =
        *reinterpret_cast<uint2*>(q1);
    *reinterpret_cast<uint2*>(zn + (size_t)(i + NPAIR) * DDIM + lane * 4) =
        *reinterpret_cast<uint2*>(q2);

    if (lane == 0) {
        e_diag[i]         = __expf(qs1 * INV_T);   // matches GEMM's bf16 self-dot
        e_diag[i + NPAIR] = __expf(qs2 * INV_T);
        pos[i]            = dd * inv1 * inv2 * INV_T;  // positive-pair term, pure fp32
    }
}

// ---------------- Kernel 2: persistent symmetric MFMA self-GEMM + sums ------
// 256 persistent blocks x 512 threads. Each block processes tiles
// [bid*2080/256, (bid+1)*2080/256) of the rt-major triangle ordering.
// Waves: w = tid>>6; wr = w>>2 (row half, 64 rows); wc = w&3 (col quarter,
// 32 cols). Per-wave acc = 4x2 f32x4 frags; per-wave B panel = 8x2 frags.
__global__ __launch_bounds__(512, 2)
void k_gemm_sumexp(const __hip_bfloat16* __restrict__ zn,
                   float* __restrict__ row_sumexp) {
    __shared__ __align__(128) __hip_bfloat16 Asmem[128 * DDIM];   // 64 KB

    const int tid  = threadIdx.x;
    const int lane = tid & 63;
    const int w    = tid >> 6;
    const int wr   = w >> 2;          // 0/1: rows wr*64..+64
    const int wc   = w & 3;           // 0..3: cols wc*32..+32
    const int lr   = lane & 15;
    const int quad = lane >> 4;

    const int t0 = (blockIdx.x * NBLK) >> 8;        // *2080/256
    const int t1 = ((blockIdx.x + 1) * NBLK) >> 8;

    // --- decode t0 -> (rt, ct); then advance incrementally (rt-major) ---
    int b = t0;
    int rt = (int)(64.5f - sqrtf(64.5f * 64.5f - 2.0f * (float)b));
    if (rt < 0) rt = 0;
    if (rt > NT - 1) rt = NT - 1;
    while (rt > 0 && NT * rt - (rt * (rt - 1)) / 2 > b) --rt;
    while (NT * (rt + 1) - ((rt + 1) * rt) / 2 <= b) ++rt;
    int ct = rt + (b - (NT * rt - (rt * (rt - 1)) / 2));

    int cur_rt = -1;
    f32x4 acc[4][2];
    int  pRow = 0, pCol = 0;
    bool pDiag = false, havePrev = false;

    // Epilogue of the tile described by (pRow, pCol, pDiag) using acc.
    // C/D layout (verified R1/R2): col = lane&15, row = quad*4 + reg.
    auto epilogue = [&]() {
        float rs[4][4], cs[2];
#pragma unroll
        for (int mi = 0; mi < 4; ++mi)
#pragma unroll
            for (int r = 0; r < 4; ++r) rs[mi][r] = 0.0f;
        cs[0] = cs[1] = 0.0f;
#pragma unroll
        for (int mi = 0; mi < 4; ++mi)
#pragma unroll
            for (int ni = 0; ni < 2; ++ni)
#pragma unroll
                for (int r = 0; r < 4; ++r) {
                    float e = __expf(acc[mi][ni][r] * INV_T);
                    rs[mi][r] += e;
                    cs[ni] += e;
                }
#pragma unroll
        for (int mi = 0; mi < 4; ++mi)
#pragma unroll
            for (int r = 0; r < 4; ++r) {
                float v = rs[mi][r];
                v += __shfl_xor(v, 1, 64);
                v += __shfl_xor(v, 2, 64);
                v += __shfl_xor(v, 4, 64);
                v += __shfl_xor(v, 8, 64);
                if (lr == 0)
                    atomicAdd(&row_sumexp[pRow + wr * 64 + mi * 16 + quad * 4 + r], v);
            }
        if (!pDiag) {
#pragma unroll
            for (int ni = 0; ni < 2; ++ni) {
                float v = cs[ni];
                v += __shfl_xor(v, 16, 64);
                v += __shfl_xor(v, 32, 64);
                if (quad == 0)
                    atomicAdd(&row_sumexp[pCol + wc * 32 + ni * 16 + lr], v);
            }
        }
    };

    for (int t = t0; t < t1; ++t) {
        const int  row_base = rt * 128;
        const int  col_base = ct * 128;
        const bool diag     = (rt == ct);
        const bool restage  = (rt != cur_rt);    // block-uniform

        if (restage) {
            __syncthreads();   // all waves done reading the old A panel
            // stage A(rt): 512 thr x 8 rounds x 16B; slot s=j*512+tid holds
            // row j*16+(tid>>5), chunk slot c'=tid&31, source chunk
            // ck = (c'&24)|((c'&7)^(row&7)).
            const int ck = (tid & 24) | ((tid & 7) ^ ((tid >> 5) & 7));
            const char* gA = (const char*)(zn + (size_t)row_base * DDIM)
                           + (tid >> 5) * (DDIM * 2) + ck * 16;
            char* lA = (char*)Asmem + tid * 16;
#pragma unroll
            for (int j = 0; j < 8; ++j)
                gload_lds16(gA + (size_t)j * 16 * (DDIM * 2), lA + j * 8192);
            cur_rt = rt;
        }

        // --- issue this tile's FULL B panel: 16 opaque 16B loads/lane.
        //     "memory" clobber pins ordering vs the epilogue atomics so the
        //     counted vmcnt below stays valid. ---
        const __hip_bfloat16* gB0 =
            zn + (size_t)(col_base + wc * 32 + lr) * DDIM + quad * 8;
        bf16x8 Bfr[8][2];
#pragma unroll
        for (int ks = 0; ks < 8; ++ks) {
            const __hip_bfloat16* p0 = gB0 + ks * 32;
            const __hip_bfloat16* p1 = p0 + 16 * DDIM;
            asm volatile("global_load_dwordx4 %0, %1, off"
                         : "=v"(Bfr[ks][0]) : "v"(p0) : "memory");
            asm volatile("global_load_dwordx4 %0, %1, off"
                         : "=v"(Bfr[ks][1]) : "v"(p1) : "memory");
        }

        // --- previous tile's epilogue runs UNDER the B-load latency ---
        if (havePrev) epilogue();
        havePrev = true; pRow = row_base; pCol = col_base; pDiag = diag;

        // --- A fragment LDS byte offsets (swizzled; verified R3) ---
        int pa[4];
#pragma unroll
        for (int mi = 0; mi < 4; ++mi)
            pa[mi] = (wr * 64 + mi * 16 + lr) * (DDIM * 2) + ((quad ^ (lr & 7)) << 4);

        bf16x8 afc[4];
        if (restage) {
            asm volatile("s_waitcnt vmcnt(0)" ::: "memory");   // drain A + B
            __syncthreads();                                    // A visible to all
#pragma unroll
            for (int mi = 0; mi < 4; ++mi)
                afc[mi] = *(const bf16x8*)((const char*)Asmem + pa[mi]);
        } else {
#pragma unroll
            for (int mi = 0; mi < 4; ++mi)
                afc[mi] = *(const bf16x8*)((const char*)Asmem + pa[mi]);
            // 16-18 epilogue atomics were issued after the 16 B loads; vmcnt
            // decrements in issue order, so outstanding<=16 => all B done.
            asm volatile("s_waitcnt vmcnt(16)" ::: "memory");
        }
        __builtin_amdgcn_sched_barrier(0);   // rule #18: no MFMA hoisting

#pragma unroll
        for (int mi = 0; mi < 4; ++mi)
#pragma unroll
            for (int ni = 0; ni < 2; ++ni)
                acc[mi][ni] = (f32x4){0.f, 0.f, 0.f, 0.f};

        // --- pure LDS+register k-loop: zero global ops, zero barriers ---
#pragma unroll
        for (int kstep = 0; kstep < 8; ++kstep) {
            bf16x8 afn[4];
            if (kstep < 7) {
                const int kn   = kstep + 1;
                const int koff = (kn >> 1) << 7;
                const int kx   = (kn & 1) << 6;
#pragma unroll
                for (int mi = 0; mi < 4; ++mi)
                    afn[mi] = *(const bf16x8*)((const char*)Asmem + ((pa[mi] ^ kx) + koff));
            }
#pragma unroll
            for (int mi = 0; mi < 4; ++mi)
#pragma unroll
                for (int ni = 0; ni < 2; ++ni)
                    acc[mi][ni] = __builtin_amdgcn_mfma_f32_16x16x32_bf16(
                        afc[mi], Bfr[kstep][ni], acc[mi][ni], 0, 0, 0);
            if (kstep < 7) {
#pragma unroll
                for (int mi = 0; mi < 4; ++mi) afc[mi] = afn[mi];
            }
        }

        if (++ct >= NT) { ++rt; ct = rt; }   // advance in the triangle
    }

    epilogue();   // last tile of the chunk
}

// ---------------- Kernel 3: tiny finisher ----------------
// grid 16 x 256: one thread per pair index.
__global__ void k_final(const float* __restrict__ row_sumexp,
                        const float* __restrict__ e_diag,
                        const float* __restrict__ pos,
                        float* __restrict__ out) {
    const int i    = blockIdx.x * 256 + threadIdx.x;   // 0..4095
    const int w    = threadIdx.x >> 6;
    const int lane = threadIdx.x & 63;

    float t = logf(row_sumexp[i] - e_diag[i])
            + logf(row_sumexp[i + NPAIR] - e_diag[i + NPAIR])
            - 2.0f * pos[i];
#pragma unroll
    for (int m = 1; m < 64; m <<= 1) t += __shfl_xor(t, m, 64);

    __shared__ float ps[4];
    if (lane == 0) ps[w] = t;
    __syncthreads();
    if (threadIdx.x == 0) {
        float s = (ps[0] + ps[1] + ps[2] + ps[3]) * (1.0f / (float)TWO_N);
        atomicAdd(out, s);
    }
}

extern "C" void kernel_launch(void* const* d_in, const int* in_sizes, int n_in,
                              void* d_out, int out_size, void* d_ws, size_t ws_size,
                              hipStream_t stream) {
    const float* z1 = (const float*)d_in[0];
    const float* z2 = (const float*)d_in[1];
    float* out = (float*)d_out;

    char* ws = (char*)d_ws;
    __hip_bfloat16* zn  = (__hip_bfloat16*)ws;                       // 4 MB
    float* row_sumexp   = (float*)(ws + (size_t)TWO_N * DDIM * 2);   // 32 KB
    float* e_diag       = row_sumexp + TWO_N;                        // 32 KB
    float* pos          = e_diag + TWO_N;                            // 16 KB

    k_normalize<<<NPAIR / 4, 256, 0, stream>>>(z1, z2, zn, e_diag, pos,
                                               row_sumexp, out);
    k_gemm_sumexp<<<GEMM_GRID, 512, 0, stream>>>(zn, row_sumexp);
    k_final<<<NPAIR / 256, 256, 0, stream>>>(row_sumexp, e_diag, pos, out);
}